// Round 10
// baseline (255.293 us; speedup 1.0000x reference)
//
#include <hip/hip_runtime.h>

typedef __bf16 bf16;
typedef __bf16 bf16x8 __attribute__((ext_vector_type(8)));
typedef __bf16 bf16x4 __attribute__((ext_vector_type(4)));
typedef float f32x4 __attribute__((ext_vector_type(4)));

#define B_ 4
#define N_ 2048
#define C_ 1024
#define H_ 16
#define HKV_ 4
#define D_ 64

// fold: 1.5 (qk_gain) * 0.125 (1/sqrt(64)) * log2(e)  -> use exp2f in softmax
#define QSCALE 0.2705053201666806f
#define NEGINF (-1.0e30f)

// ---------------------------------------------------------------------------
// Weight prep: w [1024 k][ncols n] f32 -> wT [n][1024 k] bf16 (+ convert).
__global__ __launch_bounds__(256) void prep_qkv(const float* __restrict__ wq,
                                                const float* __restrict__ wk,
                                                const float* __restrict__ wv,
                                                bf16* __restrict__ wT) {
  __shared__ __align__(16) bf16 lds[64 * 72];
  int bx = blockIdx.x;
  const float* w;
  int ncols, tk, tn, nbase;
  if (bx < 256) {
    w = wq; ncols = 1024; tk = bx >> 4; tn = bx & 15; nbase = 0;
  } else if (bx < 320) {
    int t = bx - 256;
    w = wk; ncols = 256; tk = t >> 2; tn = t & 3; nbase = 1024;
  } else {
    int t = bx - 320;
    w = wv; ncols = 256; tk = t >> 2; tn = t & 3; nbase = 1280;
  }
  int tid = threadIdx.x;
#pragma unroll
  for (int i = 0; i < 4; ++i) {
    int c = tid + i * 256;
    int kr = c >> 4, n4 = (c & 15) * 4;
    f32x4 v = *(const f32x4*)(w + (size_t)(tk * 64 + kr) * ncols + tn * 64 + n4);
    bf16x4 b;
#pragma unroll
    for (int j = 0; j < 4; ++j) b[j] = (bf16)v[j];
    *(bf16x4*)(lds + kr * 72 + n4) = b;
  }
  __syncthreads();
#pragma unroll
  for (int i = 0; i < 2; ++i) {
    int c = tid + i * 256;
    int n = c >> 3, koff = (c & 7) * 8;
    bf16x8 tv;
#pragma unroll
    for (int j = 0; j < 8; ++j) tv[j] = lds[(koff + j) * 72 + n];
    *(bf16x8*)(wT + (size_t)(nbase + tn * 64 + n) * 1024 + tk * 64 + koff) = tv;
  }
}

// Single-matrix variant for wo (1024x1024), launched after attn (aliases vt).
__global__ __launch_bounds__(256) void prep_wo(const float* __restrict__ w,
                                               bf16* __restrict__ wT) {
  __shared__ __align__(16) bf16 lds[64 * 72];
  int tk = blockIdx.x >> 4, tn = blockIdx.x & 15;
  int tid = threadIdx.x;
#pragma unroll
  for (int i = 0; i < 4; ++i) {
    int c = tid + i * 256;
    int kr = c >> 4, n4 = (c & 15) * 4;
    f32x4 v = *(const f32x4*)(w + (size_t)(tk * 64 + kr) * 1024 + tn * 64 + n4);
    bf16x4 b;
#pragma unroll
    for (int j = 0; j < 4; ++j) b[j] = (bf16)v[j];
    *(bf16x4*)(lds + kr * 72 + n4) = b;
  }
  __syncthreads();
#pragma unroll
  for (int i = 0; i < 2; ++i) {
    int c = tid + i * 256;
    int n = c >> 3, koff = (c & 7) * 8;
    bf16x8 tv;
#pragma unroll
    for (int j = 0; j < 8; ++j) tv[j] = lds[(koff + j) * 72 + n];
    *(bf16x8*)(wT + (size_t)(tn * 64 + n) * 1024 + tk * 64 + koff) = tv;
  }
}

// ---------------------------------------------------------------------------
// Fused QKV projection, bf16 pre-transposed weights. Grid (64, 12).
// Attn-style async staging: next k-tile's global loads are issued into
// registers BEFORE the MFMA section; LDS writes after a raw s_barrier.
__global__ __launch_bounds__(256) void gemm_qkv(const float* __restrict__ x,
                                                const bf16* __restrict__ wT,
                                                bf16* __restrict__ qb,
                                                bf16* __restrict__ kvb) {
  __shared__ __align__(16) bf16 As[128 * 72];
  __shared__ __align__(16) bf16 Bs[128 * 72];
  int by = blockIdx.y;
  int n0 = by * 128;  // row into wT[1536][1024]
  bf16* Out;
  int ostride, ocol0;
  if (by < 8) {
    Out = qb; ostride = 1024; ocol0 = by * 128;
  } else if (by < 10) {
    Out = kvb; ostride = 512; ocol0 = (by - 8) * 128;
  } else {
    Out = kvb; ostride = 512; ocol0 = 256 + (by - 10) * 128;
  }
  int m0 = blockIdx.x * 128;
  int tid = threadIdx.x;
  int wave = tid >> 6, lane = tid & 63;
  int quad = lane >> 4, lr = lane & 15;
  int wr = (wave >> 1) * 64, wc = (wave & 1) * 64;
  int arow = tid >> 4, aoff = (tid & 15) * 4;  // A staging coords (+16 rows x8)
  int brow = tid >> 3, boff = (tid & 7) * 8;   // B staging coords (+32 rows x4)

  f32x4 acc[4][4];
  const f32x4 z = {0.f, 0.f, 0.f, 0.f};
#pragma unroll
  for (int i = 0; i < 4; ++i)
#pragma unroll
    for (int j = 0; j < 4; ++j) acc[i][j] = z;

  f32x4 sa[8];
  bf16x8 sb[4];
  // ---- prologue: stage k0 = 0
#pragma unroll
  for (int i = 0; i < 8; ++i)
    sa[i] = *(const f32x4*)(x + (size_t)(m0 + arow + i * 16) * 1024 + aoff);
#pragma unroll
  for (int i = 0; i < 4; ++i)
    sb[i] = *(const bf16x8*)(wT + (size_t)(n0 + brow + i * 32) * 1024 + boff);
#pragma unroll
  for (int i = 0; i < 8; ++i) {
    bf16x4 a16;
#pragma unroll
    for (int j = 0; j < 4; ++j) a16[j] = (bf16)sa[i][j];
    *(bf16x4*)(As + (arow + i * 16) * 72 + aoff) = a16;
  }
#pragma unroll
  for (int i = 0; i < 4; ++i) *(bf16x8*)(Bs + (brow + i * 32) * 72 + boff) = sb[i];
  asm volatile("s_waitcnt lgkmcnt(0)" ::: "memory");
  __builtin_amdgcn_s_barrier();
  __builtin_amdgcn_sched_barrier(0);

  for (int k0 = 0; k0 < 1024; k0 += 64) {
    bool pf = (k0 + 64 < 1024);
    if (pf) {
#pragma unroll
      for (int i = 0; i < 8; ++i)
        sa[i] = *(const f32x4*)(x + (size_t)(m0 + arow + i * 16) * 1024 + k0 + 64 + aoff);
#pragma unroll
      for (int i = 0; i < 4; ++i)
        sb[i] = *(const bf16x8*)(wT + (size_t)(n0 + brow + i * 32) * 1024 + k0 + 64 + boff);
    }
#pragma unroll
    for (int kx = 0; kx < 2; ++kx) {
      bf16x8 af[4], bfr[4];
#pragma unroll
      for (int t = 0; t < 4; ++t) {
        af[t] = *(const bf16x8*)(As + (wr + t * 16 + lr) * 72 + kx * 32 + quad * 8);
        bfr[t] = *(const bf16x8*)(Bs + (wc + t * 16 + lr) * 72 + kx * 32 + quad * 8);
      }
      __builtin_amdgcn_s_setprio(1);
#pragma unroll
      for (int rt = 0; rt < 4; ++rt)
#pragma unroll
        for (int ct = 0; ct < 4; ++ct)
          acc[rt][ct] = __builtin_amdgcn_mfma_f32_16x16x32_bf16(af[rt], bfr[ct],
                                                                acc[rt][ct], 0, 0, 0);
      __builtin_amdgcn_s_setprio(0);
    }
    // all waves consumed As/Bs for tile k0 (ds_reads drained before MFMAs)
    __builtin_amdgcn_s_barrier();
    __builtin_amdgcn_sched_barrier(0);
    if (pf) {
      // compiler inserts s_waitcnt vmcnt as sa/sb are first used here
#pragma unroll
      for (int i = 0; i < 8; ++i) {
        bf16x4 a16;
#pragma unroll
        for (int j = 0; j < 4; ++j) a16[j] = (bf16)sa[i][j];
        *(bf16x4*)(As + (arow + i * 16) * 72 + aoff) = a16;
      }
#pragma unroll
      for (int i = 0; i < 4; ++i) *(bf16x8*)(Bs + (brow + i * 32) * 72 + boff) = sb[i];
      asm volatile("s_waitcnt lgkmcnt(0)" ::: "memory");
    }
    __builtin_amdgcn_s_barrier();
    __builtin_amdgcn_sched_barrier(0);
  }
#pragma unroll
  for (int rt = 0; rt < 4; ++rt)
#pragma unroll
    for (int ct = 0; ct < 4; ++ct)
#pragma unroll
      for (int r = 0; r < 4; ++r) {
        int row = m0 + wr + rt * 16 + quad * 4 + r;
        int col = ocol0 + wc + ct * 16 + lr;
        Out[(size_t)row * ostride + col] = (bf16)acc[rt][ct][r];
      }
}

// ---------------------------------------------------------------------------
// Output projection: A = attn output (bf16), B^T = woT bf16, C = float out.
// Same async-staging structure (both operands bf16).
__global__ __launch_bounds__(256) void gemm_out(const bf16* __restrict__ A,
                                                const bf16* __restrict__ Bt,
                                                float* __restrict__ C) {
  __shared__ __align__(16) bf16 As[128 * 72];
  __shared__ __align__(16) bf16 Bs[128 * 72];
  int m0 = blockIdx.x * 128, n0 = blockIdx.y * 128;
  int tid = threadIdx.x;
  int wave = tid >> 6, lane = tid & 63;
  int quad = lane >> 4, lr = lane & 15;
  int wr = (wave >> 1) * 64, wc = (wave & 1) * 64;
  int brow = tid >> 3, boff = (tid & 7) * 8;

  f32x4 acc[4][4];
  const f32x4 z = {0.f, 0.f, 0.f, 0.f};
#pragma unroll
  for (int i = 0; i < 4; ++i)
#pragma unroll
    for (int j = 0; j < 4; ++j) acc[i][j] = z;

  bf16x8 sa[4], sb[4];
#pragma unroll
  for (int i = 0; i < 4; ++i) {
    sa[i] = *(const bf16x8*)(A + (size_t)(m0 + brow + i * 32) * 1024 + boff);
    sb[i] = *(const bf16x8*)(Bt + (size_t)(n0 + brow + i * 32) * 1024 + boff);
  }
#pragma unroll
  for (int i = 0; i < 4; ++i) {
    *(bf16x8*)(As + (brow + i * 32) * 72 + boff) = sa[i];
    *(bf16x8*)(Bs + (brow + i * 32) * 72 + boff) = sb[i];
  }
  asm volatile("s_waitcnt lgkmcnt(0)" ::: "memory");
  __builtin_amdgcn_s_barrier();
  __builtin_amdgcn_sched_barrier(0);

  for (int k0 = 0; k0 < 1024; k0 += 64) {
    bool pf = (k0 + 64 < 1024);
    if (pf) {
#pragma unroll
      for (int i = 0; i < 4; ++i) {
        sa[i] = *(const bf16x8*)(A + (size_t)(m0 + brow + i * 32) * 1024 + k0 + 64 + boff);
        sb[i] = *(const bf16x8*)(Bt + (size_t)(n0 + brow + i * 32) * 1024 + k0 + 64 + boff);
      }
    }
#pragma unroll
    for (int kx = 0; kx < 2; ++kx) {
      bf16x8 af[4], bfr[4];
#pragma unroll
      for (int t = 0; t < 4; ++t) {
        af[t] = *(const bf16x8*)(As + (wr + t * 16 + lr) * 72 + kx * 32 + quad * 8);
        bfr[t] = *(const bf16x8*)(Bs + (wc + t * 16 + lr) * 72 + kx * 32 + quad * 8);
      }
      __builtin_amdgcn_s_setprio(1);
#pragma unroll
      for (int rt = 0; rt < 4; ++rt)
#pragma unroll
        for (int ct = 0; ct < 4; ++ct)
          acc[rt][ct] = __builtin_amdgcn_mfma_f32_16x16x32_bf16(af[rt], bfr[ct],
                                                                acc[rt][ct], 0, 0, 0);
      __builtin_amdgcn_s_setprio(0);
    }
    __builtin_amdgcn_s_barrier();
    __builtin_amdgcn_sched_barrier(0);
    if (pf) {
#pragma unroll
      for (int i = 0; i < 4; ++i) {
        *(bf16x8*)(As + (brow + i * 32) * 72 + boff) = sa[i];
        *(bf16x8*)(Bs + (brow + i * 32) * 72 + boff) = sb[i];
      }
      asm volatile("s_waitcnt lgkmcnt(0)" ::: "memory");
    }
    __builtin_amdgcn_s_barrier();
    __builtin_amdgcn_sched_barrier(0);
  }
#pragma unroll
  for (int rt = 0; rt < 4; ++rt)
#pragma unroll
    for (int ct = 0; ct < 4; ++ct)
#pragma unroll
      for (int r = 0; r < 4; ++r) {
        int row = m0 + wr + rt * 16 + quad * 4 + r;
        int col = n0 + wc + ct * 16 + lr;
        C[(size_t)row * 1024 + col] = acc[rt][ct][r];
      }
}

// ---------------------------------------------------------------------------
// V transpose: kv [B*N][512] -> vt [B][HKV][D][N].
__global__ __launch_bounds__(256) void transpose_v(const bf16* __restrict__ kv,
                                                   bf16* __restrict__ vt) {
  __shared__ __align__(16) bf16 lds[64 * 72];
  int nt = blockIdx.x;
  int bh = blockIdx.y;
  int b = bh >> 2, hkv = bh & 3;
  int tid = threadIdx.x;
#pragma unroll
  for (int i = 0; i < 2; ++i) {
    int c = tid + i * 256;
    int tok = c >> 3, off = (c & 7) * 8;
    *(bf16x8*)(lds + tok * 72 + off) =
        *(const bf16x8*)(kv + (size_t)(b * N_ + nt * 64 + tok) * 512 + 256 + hkv * 64 + off);
  }
  __syncthreads();
#pragma unroll
  for (int i = 0; i < 2; ++i) {
    int c = tid + i * 256;
    int d = c >> 3, toff = (c & 7) * 8;
    bf16x8 tv;
#pragma unroll
    for (int j = 0; j < 8; ++j) tv[j] = lds[(toff + j) * 72 + d];
    *(bf16x8*)(vt + ((size_t)bh * 64 + d) * N_ + nt * 64 + toff) = tv;
  }
}

// ---------------------------------------------------------------------------
// Per-head RMSNorm + RoPE, in place — VECTORIZED (G13): 8 lanes per head,
// bf16x8 per lane (16 B). RMS reduce = 3 shfls in the octet; RoPE partner
// d+-32 = shfl_xor(xn, 4); sign = -(e<4). Grid 5120 x 256 (32 heads/block).
__global__ __launch_bounds__(256) void norm_rope(bf16* __restrict__ q,
                                                 bf16* __restrict__ kv) {
  int tid = threadIdx.x;
  int g = (blockIdx.x << 5) + (tid >> 3);  // global head id, 163840 total
  int e = tid & 7;                          // octet index within head
  int t = g / 20;
  int sub = g - t * 20;
  int n = t & (N_ - 1);
  bf16* ptr;
  float oscale;
  if (sub < 16) {
    ptr = q + (size_t)t * 1024 + sub * 64;
    oscale = QSCALE;
  } else {
    ptr = kv + (size_t)t * 512 + (sub - 16) * 64;
    oscale = 1.0f;
  }
  bf16x8 v = *(const bf16x8*)(ptr + e * 8);
  float xv[8];
  float ss = 0.f;
#pragma unroll
  for (int i = 0; i < 8; ++i) {
    xv[i] = (float)v[i];
    ss += xv[i] * xv[i];
  }
  ss += __shfl_xor(ss, 1);
  ss += __shfl_xor(ss, 2);
  ss += __shfl_xor(ss, 4);
  float rn = rsqrtf(ss * (1.0f / 64.0f) + 1.1920929e-07f);
  float base = (float)((e & 3) * 8);  // d mod 32 base for this octet
  bf16x8 o;
#pragma unroll
  for (int i = 0; i < 8; ++i) {
    float xn = xv[i] * rn;
    float pr = __shfl_xor(xn, 4);  // partner element d +- 32 (rn is head-uniform)
    float rot = (e < 4) ? -pr : pr;
    float ang = (float)n * exp2f(-0.41524101186092029f * (base + (float)i));
    float sv, cv;
    __sincosf(ang, &sv, &cv);
    o[i] = (bf16)((xn * cv + rot * sv) * oscale);
  }
  *(bf16x8*)(ptr + e * 8) = o;
}

// ---------------------------------------------------------------------------
// Causal flash attention with GQA — TRANSPOSED dataflow (S^T / O^T),
// XOR-swizzled LDS, no-shift softmax, complement-pair schedule + XCD swizzle.
// Round-9: DOUBLE-BUFFERED Ks/Vs -> ONE barrier per k-tile.
//   Writes for tile kt+1 go to buf[cur^1] while compute reads buf[cur] —
//   no WAR hazard, so the LDS write no longer sits between two rendezvous.
//   Loop: compute(cur) -> write(cur^1) (vmcnt waits ~0: loads were issued a
//   full tile earlier) -> issue loads kt+2 -> lgkm drain -> barrier -> swap.
//   LDS = 2*8K (Ks) + 2*8K (Vs) + 8K (Ps) = 40960 B exactly -> 4 blocks/CU.
__global__ __launch_bounds__(256) void attn(bf16* __restrict__ q,
                                            const bf16* __restrict__ kv,
                                            const bf16* __restrict__ vt) {
  __shared__ __align__(16) bf16 Ks[2][64 * 64];  // [buf][key][d], swizzled
  __shared__ __align__(16) bf16 Vs[2][64 * 64];  // [buf][d][key], swizzled
  __shared__ __align__(16) bf16 Ps[64 * 64];     // [q-row][key], swizzled
  int bid = blockIdx.x;
  int orig = (bid & 7) * 128 + (bid >> 3);  // bijective (1024 % 8 == 0)
  int grp = orig >> 6;                      // (b,hkv) group, 0..15
  int inner = orig & 63;
  int b = grp >> 2, hkv = grp & 3;
  int h = hkv * 4 + (inner & 3);
  int p = inner >> 2;                       // pair index, 0..15
  int tid = threadIdx.x;
  int wave = tid >> 6, lane = tid & 63;
  int quad = lane >> 4, lr = lane & 15;
  int srow = tid >> 3, soff = (tid & 7) * 8;
  int su = ((tid & 7) ^ (srow & 7)) * 8;  // swizzled LDS unit (same for srow+32)
  int e7 = lr & 7;                        // read-side row XOR key
  const f32x4 z = {0.f, 0.f, 0.f, 0.f};

#pragma unroll 1
  for (int s = 0; s < 2; ++s) {
    int j = s ? (31 - p) : p;  // q-tile index; costs sum to 33 units
    __syncthreads();           // prev sub-item's last reads done before re-stage
    int qrow0 = j * 64 + wave * 16;  // this wave's first q-row
    int nkt = j + 1;

    // Q fragments (B-operand = Q^T): lane holds Q[qrow0+lr][kx*32+quad*8..]
    bf16x8 qf[2];
#pragma unroll
    for (int kx = 0; kx < 2; ++kx)
      qf[kx] = *(const bf16x8*)(
          q + ((size_t)(b * N_ + qrow0 + lr) * H_ + h) * D_ + kx * 32 + quad * 8);

    f32x4 acc[4];  // acc[dt] = O^T tile: row d=dt*16+quad*4+r, col qrow=lr
    float l_i = 0.f;
#pragma unroll
    for (int dt = 0; dt < 4; ++dt) acc[dt] = z;

    // staging pointers (strength-reduced; advance per tile)
    const bf16* kp = kv + (size_t)(b * N_ + srow) * 512 + hkv * 64 + soff;
    const bf16* vp = vt + ((size_t)(b * HKV_ + hkv) * 64 + srow) * N_ + soff;

    // ---- prologue: stage tile 0 into buf0; issue tile-1 loads
    bf16x8 sk0, sk1, sv0, sv1;
    sk0 = *(const bf16x8*)(kp);
    sk1 = *(const bf16x8*)(kp + 32 * 512);
    sv0 = *(const bf16x8*)(vp);
    sv1 = *(const bf16x8*)(vp + 32 * N_);
    *(bf16x8*)(Ks[0] + srow * 64 + su) = sk0;
    *(bf16x8*)(Ks[0] + (srow + 32) * 64 + su) = sk1;
    *(bf16x8*)(Vs[0] + srow * 64 + su) = sv0;
    *(bf16x8*)(Vs[0] + (srow + 32) * 64 + su) = sv1;
    if (nkt > 1) {
      kp += 64 * 512;
      vp += 64;
      sk0 = *(const bf16x8*)(kp);
      sk1 = *(const bf16x8*)(kp + 32 * 512);
      sv0 = *(const bf16x8*)(vp);
      sv1 = *(const bf16x8*)(vp + 32 * N_);
    }
    asm volatile("s_waitcnt lgkmcnt(0)" ::: "memory");
    __builtin_amdgcn_s_barrier();
    __builtin_amdgcn_sched_barrier(0);

    int cur = 0;
    for (int kt = 0; kt < nkt; ++kt) {
      const bf16* Kc = Ks[cur];
      const bf16* Vc = Vs[cur];
      // S^T = K·Q^T: st[ct] — key = kt*64 + ct*16 + quad*4 + r, qrow col = lr
      f32x4 st[4];
#pragma unroll
      for (int ct = 0; ct < 4; ++ct) st[ct] = z;
#pragma unroll
      for (int kx = 0; kx < 2; ++kx) {
        bf16x8 kf[4];
#pragma unroll
        for (int ct = 0; ct < 4; ++ct)
          kf[ct] = *(const bf16x8*)(Kc + (ct * 16 + lr) * 64 + (((kx * 4 + quad) ^ e7) * 8));
        __builtin_amdgcn_s_setprio(1);
#pragma unroll
        for (int ct = 0; ct < 4; ++ct)
          st[ct] = __builtin_amdgcn_mfma_f32_16x16x32_bf16(kf[ct], qf[kx], st[ct], 0, 0, 0);
        __builtin_amdgcn_s_setprio(0);
      }
      // Causal mask — only the diagonal tile kt == j crosses the diagonal
      if (kt == j) {
        int qrow = qrow0 + lr;
#pragma unroll
        for (int ct = 0; ct < 4; ++ct)
#pragma unroll
          for (int r = 0; r < 4; ++r) {
            int key = kt * 64 + ct * 16 + quad * 4 + r;
            if (key > qrow) st[ct][r] = NEGINF;
          }
      }
      // No-shift softmax: p = exp2(s) directly (|s| <= 17.32 by RMS bound);
      // masked entries exp2(-1e30) = 0. l accumulates unnormalized.
      float rs = 0.f;
#pragma unroll
      for (int ct = 0; ct < 4; ++ct)
#pragma unroll
        for (int r = 0; r < 4; ++r) {
          float pv = exp2f(st[ct][r]);
          st[ct][r] = pv;
          rs += pv;
        }
      rs += __shfl_xor(rs, 16);
      rs += __shfl_xor(rs, 32);
      l_i += rs;
      // P^T -> Ps[qrow][key] (swizzled): b64 writes, keys quad*4+r contiguous
#pragma unroll
      for (int ct = 0; ct < 4; ++ct) {
        bf16x4 pk;
#pragma unroll
        for (int r = 0; r < 4; ++r) pk[r] = (bf16)st[ct][r];
        int pu = (((ct * 2) + (quad >> 1)) ^ e7) * 8 + (quad & 1) * 4;
        *(bf16x4*)(Ps + (wave * 16 + lr) * 64 + pu) = pk;
      }
      // Wave-local LDS ordering (rows wave-private, guard wave-uniform)
      asm volatile("s_waitcnt lgkmcnt(0)" ::: "memory");
      // O^T += V^T·P^T
#pragma unroll
      for (int kx = 0; kx < 2; ++kx) {
        bf16x8 vf[4], pfr;
#pragma unroll
        for (int dt = 0; dt < 4; ++dt)
          vf[dt] = *(const bf16x8*)(Vc + (dt * 16 + lr) * 64 + (((kx * 4 + quad) ^ e7) * 8));
        pfr = *(const bf16x8*)(Ps + (wave * 16 + lr) * 64 + (((kx * 4 + quad) ^ e7) * 8));
        __builtin_amdgcn_s_setprio(1);
#pragma unroll
        for (int dt = 0; dt < 4; ++dt)
          acc[dt] = __builtin_amdgcn_mfma_f32_16x16x32_bf16(vf[dt], pfr, acc[dt], 0, 0, 0);
        __builtin_amdgcn_s_setprio(0);
      }

      // ---- stage tile kt+1 into the OTHER buffer (no WAR: readers use cur).
      // vmcnt wait is ~0 — its loads were issued a full tile ago. Then issue
      // tile kt+2 loads so they too have a full tile in flight.
      bool pf = (kt + 1 < nkt);
      if (pf) {
        bf16* Kn = Ks[cur ^ 1];
        bf16* Vn = Vs[cur ^ 1];
        *(bf16x8*)(Kn + srow * 64 + su) = sk0;
        *(bf16x8*)(Kn + (srow + 32) * 64 + su) = sk1;
        *(bf16x8*)(Vn + srow * 64 + su) = sv0;
        *(bf16x8*)(Vn + (srow + 32) * 64 + su) = sv1;
        if (kt + 2 < nkt) {
          kp += 64 * 512;
          vp += 64;
          sk0 = *(const bf16x8*)(kp);
          sk1 = *(const bf16x8*)(kp + 32 * 512);
          sv0 = *(const bf16x8*)(vp);
          sv1 = *(const bf16x8*)(vp + 32 * N_);
        }
        asm volatile("s_waitcnt lgkmcnt(0)" ::: "memory");
      }
      // ONE barrier per tile: all waves wrote buf^1 and finished reading cur.
      __builtin_amdgcn_s_barrier();
      __builtin_amdgcn_sched_barrier(0);
      cur ^= 1;
    }

    // Epilogue: y = O / l — lane owns q-row lr, d = dt*16+quad*4+r
    float inv = 1.0f / l_i;
    int qrow = qrow0 + lr;
#pragma unroll
    for (int dt = 0; dt < 4; ++dt) {
      bf16x4 ov;
#pragma unroll
      for (int r = 0; r < 4; ++r) ov[r] = (bf16)(acc[dt][r] * inv);
      *(bf16x4*)(q + ((size_t)(b * N_ + qrow) * H_ + h) * D_ + dt * 16 + quad * 4) = ov;
    }
  }
}

// ---------------------------------------------------------------------------
extern "C" void kernel_launch(void* const* d_in, const int* in_sizes, int n_in,
                              void* d_out, int out_size, void* d_ws, size_t ws_size,
                              hipStream_t stream) {
  // Inputs FP32; output FP32. Intermediates bf16.
  const float* x = (const float*)d_in[0];
  const float* wq = (const float*)d_in[1];
  const float* wk = (const float*)d_in[2];
  const float* wv = (const float*)d_in[3];
  const float* wo = (const float*)d_in[4];
  float* out = (float*)d_out;
  char* ws = (char*)d_ws;
  // ws (28 MB): q/y 16 MB [0,16M) | kv 8 MB [16M,24M) | region [24M,28M) is
  // time-shared: wqkvT (3 MB) -> vt (4 MB) -> woT (2 MB).
  bf16* q = (bf16*)(ws);
  bf16* kv = (bf16*)(ws + 16777216);
  bf16* vt = (bf16*)(ws + 25165824);
  bf16* wqkvT = (bf16*)(ws + 25165824);
  bf16* woT = (bf16*)(ws + 25165824);

  prep_qkv<<<dim3(384), 256, 0, stream>>>(wq, wk, wv, wqkvT);
  gemm_qkv<<<dim3(64, 12), 256, 0, stream>>>(x, wqkvT, q, kv);
  norm_rope<<<dim3(5120), 256, 0, stream>>>(q, kv);
  transpose_v<<<dim3(32, 16), 256, 0, stream>>>(kv, vt);
  attn<<<dim3(1024), 256, 0, stream>>>(q, kv, vt);
  prep_wo<<<dim3(256), 256, 0, stream>>>(wo, woT);
  gemm_out<<<dim3(64, 8), 256, 0, stream>>>(q, woT, out);
}

// Round 12
// 234.275 us; speedup vs baseline: 1.0897x; 1.0897x over previous
//
#include <hip/hip_runtime.h>

typedef __bf16 bf16;
typedef __bf16 bf16x8 __attribute__((ext_vector_type(8)));
typedef __bf16 bf16x4 __attribute__((ext_vector_type(4)));
typedef float f32x4 __attribute__((ext_vector_type(4)));

#define B_ 4
#define N_ 2048
#define C_ 1024
#define H_ 16
#define HKV_ 4
#define D_ 64

// fold: 1.5 (qk_gain) * 0.125 (1/sqrt(64)) * log2(e)  -> use exp2f in softmax
#define QSCALE 0.2705053201666806f
#define NEGINF (-1.0e30f)
#define ROPE_C (-0.41524101186092029f)  // -log2(10000)/32

// ---------------------------------------------------------------------------
// Weight prep: w [1024 k][ncols n] f32 -> wT [n][1024 k] bf16 (+ convert).
__global__ __launch_bounds__(256) void prep_qkv(const float* __restrict__ wq,
                                                const float* __restrict__ wk,
                                                const float* __restrict__ wv,
                                                bf16* __restrict__ wT) {
  __shared__ __align__(16) bf16 lds[64 * 72];
  int bx = blockIdx.x;
  const float* w;
  int ncols, tk, tn, nbase;
  if (bx < 256) {
    w = wq; ncols = 1024; tk = bx >> 4; tn = bx & 15; nbase = 0;
  } else if (bx < 320) {
    int t = bx - 256;
    w = wk; ncols = 256; tk = t >> 2; tn = t & 3; nbase = 1024;
  } else {
    int t = bx - 320;
    w = wv; ncols = 256; tk = t >> 2; tn = t & 3; nbase = 1280;
  }
  int tid = threadIdx.x;
#pragma unroll
  for (int i = 0; i < 4; ++i) {
    int c = tid + i * 256;
    int kr = c >> 4, n4 = (c & 15) * 4;
    f32x4 v = *(const f32x4*)(w + (size_t)(tk * 64 + kr) * ncols + tn * 64 + n4);
    bf16x4 b;
#pragma unroll
    for (int j = 0; j < 4; ++j) b[j] = (bf16)v[j];
    *(bf16x4*)(lds + kr * 72 + n4) = b;
  }
  __syncthreads();
#pragma unroll
  for (int i = 0; i < 2; ++i) {
    int c = tid + i * 256;
    int n = c >> 3, koff = (c & 7) * 8;
    bf16x8 tv;
#pragma unroll
    for (int j = 0; j < 8; ++j) tv[j] = lds[(koff + j) * 72 + n];
    *(bf16x8*)(wT + (size_t)(nbase + tn * 64 + n) * 1024 + tk * 64 + koff) = tv;
  }
}

// Single-matrix variant for wo (1024x1024); aliases wqkvT (dead after qkv).
__global__ __launch_bounds__(256) void prep_wo(const float* __restrict__ w,
                                               bf16* __restrict__ wT) {
  __shared__ __align__(16) bf16 lds[64 * 72];
  int tk = blockIdx.x >> 4, tn = blockIdx.x & 15;
  int tid = threadIdx.x;
#pragma unroll
  for (int i = 0; i < 4; ++i) {
    int c = tid + i * 256;
    int kr = c >> 4, n4 = (c & 15) * 4;
    f32x4 v = *(const f32x4*)(w + (size_t)(tk * 64 + kr) * 1024 + tn * 64 + n4);
    bf16x4 b;
#pragma unroll
    for (int j = 0; j < 4; ++j) b[j] = (bf16)v[j];
    *(bf16x4*)(lds + kr * 72 + n4) = b;
  }
  __syncthreads();
#pragma unroll
  for (int i = 0; i < 2; ++i) {
    int c = tid + i * 256;
    int n = c >> 3, koff = (c & 7) * 8;
    bf16x8 tv;
#pragma unroll
    for (int j = 0; j < 8; ++j) tv[j] = lds[(koff + j) * 72 + n];
    *(bf16x8*)(wT + (size_t)(tn * 64 + n) * 1024 + tk * 64 + koff) = tv;
  }
}

// ---------------------------------------------------------------------------
// Fused QKV projection + RMSNorm + RoPE + V-transpose. Grid (64, 12).
//   by 0..7 : q  -> RMSNorm+RoPE+QSCALE epilogue -> qb   (ostride 1024)
//   by 8..9 : k  -> RMSNorm+RoPE epilogue        -> kvK  (ostride 256)
//   by 10..11: v -> transposed store             -> vt [b][hkv][d][tok]
// A wave's 64 output cols = exactly one head, so the norm reduce is 4
// in-register squares + 4 shfl_xor (over lr); RoPE partner d+-32 = ct^2
// (same lane). This deletes the norm_rope and transpose_v kernels and
// norms unrounded f32 acc (closer to the f32 reference than the old
// bf16 round-trip).
__global__ __launch_bounds__(256) void gemm_qkv(const float* __restrict__ x,
                                                const bf16* __restrict__ wT,
                                                bf16* __restrict__ qb,
                                                bf16* __restrict__ kvK,
                                                bf16* __restrict__ vt) {
  __shared__ __align__(16) bf16 As[128 * 72];
  __shared__ __align__(16) bf16 Bs[128 * 72];
  int by = blockIdx.y;
  int n0 = by * 128;  // row into wT[1536][1024]
  int m0 = blockIdx.x * 128;
  int tid = threadIdx.x;
  int wave = tid >> 6, lane = tid & 63;
  int quad = lane >> 4, lr = lane & 15;
  int wr = (wave >> 1) * 64, wc = (wave & 1) * 64;
  int arow = tid >> 4, aoff = (tid & 15) * 4;
  int brow = tid >> 3, boff = (tid & 7) * 8;

  f32x4 acc[4][4];
  const f32x4 z = {0.f, 0.f, 0.f, 0.f};
#pragma unroll
  for (int i = 0; i < 4; ++i)
#pragma unroll
    for (int j = 0; j < 4; ++j) acc[i][j] = z;

  f32x4 sa[8];
  bf16x8 sb[4];
  // ---- prologue: stage k0 = 0
#pragma unroll
  for (int i = 0; i < 8; ++i)
    sa[i] = *(const f32x4*)(x + (size_t)(m0 + arow + i * 16) * 1024 + aoff);
#pragma unroll
  for (int i = 0; i < 4; ++i)
    sb[i] = *(const bf16x8*)(wT + (size_t)(n0 + brow + i * 32) * 1024 + boff);
#pragma unroll
  for (int i = 0; i < 8; ++i) {
    bf16x4 a16;
#pragma unroll
    for (int j = 0; j < 4; ++j) a16[j] = (bf16)sa[i][j];
    *(bf16x4*)(As + (arow + i * 16) * 72 + aoff) = a16;
  }
#pragma unroll
  for (int i = 0; i < 4; ++i) *(bf16x8*)(Bs + (brow + i * 32) * 72 + boff) = sb[i];
  asm volatile("s_waitcnt lgkmcnt(0)" ::: "memory");
  __builtin_amdgcn_s_barrier();
  __builtin_amdgcn_sched_barrier(0);

  for (int k0 = 0; k0 < 1024; k0 += 64) {
    bool pf = (k0 + 64 < 1024);
    if (pf) {
#pragma unroll
      for (int i = 0; i < 8; ++i)
        sa[i] = *(const f32x4*)(x + (size_t)(m0 + arow + i * 16) * 1024 + k0 + 64 + aoff);
#pragma unroll
      for (int i = 0; i < 4; ++i)
        sb[i] = *(const bf16x8*)(wT + (size_t)(n0 + brow + i * 32) * 1024 + k0 + 64 + boff);
    }
#pragma unroll
    for (int kx = 0; kx < 2; ++kx) {
      bf16x8 af[4], bfr[4];
#pragma unroll
      for (int t = 0; t < 4; ++t) {
        af[t] = *(const bf16x8*)(As + (wr + t * 16 + lr) * 72 + kx * 32 + quad * 8);
        bfr[t] = *(const bf16x8*)(Bs + (wc + t * 16 + lr) * 72 + kx * 32 + quad * 8);
      }
      __builtin_amdgcn_s_setprio(1);
#pragma unroll
      for (int rt = 0; rt < 4; ++rt)
#pragma unroll
        for (int ct = 0; ct < 4; ++ct)
          acc[rt][ct] = __builtin_amdgcn_mfma_f32_16x16x32_bf16(af[rt], bfr[ct],
                                                                acc[rt][ct], 0, 0, 0);
      __builtin_amdgcn_s_setprio(0);
    }
    __builtin_amdgcn_s_barrier();
    __builtin_amdgcn_sched_barrier(0);
    if (pf) {
#pragma unroll
      for (int i = 0; i < 8; ++i) {
        bf16x4 a16;
#pragma unroll
        for (int j = 0; j < 4; ++j) a16[j] = (bf16)sa[i][j];
        *(bf16x4*)(As + (arow + i * 16) * 72 + aoff) = a16;
      }
#pragma unroll
      for (int i = 0; i < 4; ++i) *(bf16x8*)(Bs + (brow + i * 32) * 72 + boff) = sb[i];
      asm volatile("s_waitcnt lgkmcnt(0)" ::: "memory");
    }
    __builtin_amdgcn_s_barrier();
    __builtin_amdgcn_sched_barrier(0);
  }

  if (by < 10) {
    // ---- q/k epilogue: RMSNorm + RoPE fused on f32 acc.
    bf16* Out;
    int ostride, ocol0;
    float oscale;
    if (by < 8) {
      Out = qb; ostride = 1024; ocol0 = by * 128; oscale = QSCALE;
    } else {
      Out = kvK; ostride = 256; ocol0 = (by - 8) * 128; oscale = 1.0f;
    }
    float if0 = exp2f(ROPE_C * (float)lr);         // d mod 32 = lr      (ct even)
    float if1 = exp2f(ROPE_C * (float)(16 + lr));  // d mod 32 = 16+lr   (ct odd)
#pragma unroll
    for (int rt = 0; rt < 4; ++rt) {
#pragma unroll
      for (int r = 0; r < 4; ++r) {
        float ss = 0.f;
#pragma unroll
        for (int ct = 0; ct < 4; ++ct) ss += acc[rt][ct][r] * acc[rt][ct][r];
        ss += __shfl_xor(ss, 1);  // sum over lr within the quad group
        ss += __shfl_xor(ss, 2);  // (rows are per-(quad,r); cols per-lr)
        ss += __shfl_xor(ss, 4);
        ss += __shfl_xor(ss, 8);
        float rn = rsqrtf(ss * (1.0f / 64.0f) + 1.1920929e-07f);
        int row = m0 + wr + rt * 16 + quad * 4 + r;
        float fn = (float)(row & (N_ - 1));
        float sv0, cv0, sv1, cv1;
        __sincosf(fn * if0, &sv0, &cv0);
        __sincosf(fn * if1, &sv1, &cv1);
#pragma unroll
        for (int ct = 0; ct < 4; ++ct) {
          float xn = acc[rt][ct][r] * rn;
          float xp = acc[rt][ct ^ 2][r] * rn;  // RoPE partner d +- 32
          float rot = (ct < 2) ? -xp : xp;     // d<32: -x[d+32]; d>=32: +x[d-32]
          float sv = (ct & 1) ? sv1 : sv0;
          float cv = (ct & 1) ? cv1 : cv0;
          int col = ocol0 + wc + ct * 16 + lr;
          Out[(size_t)row * ostride + col] = (bf16)((xn * cv + rot * sv) * oscale);
        }
      }
    }
  } else {
    // ---- v epilogue: transposed store to vt [b][hkv][d][tok].
    // acc's r-axis = 4 contiguous tokens = vt's fastest dim -> bf16x4 stores.
    int b = m0 >> 11;                       // block's 128 rows lie in one batch
    int tokb = (m0 & (N_ - 1)) + wr;
    int hv = (by - 10) * 2 + (wc >> 6);     // this wave's v-head
#pragma unroll
    for (int rt = 0; rt < 4; ++rt)
#pragma unroll
      for (int ct = 0; ct < 4; ++ct) {
        bf16x4 ov;
#pragma unroll
        for (int r = 0; r < 4; ++r) ov[r] = (bf16)acc[rt][ct][r];
        int d = ct * 16 + lr;
        int tok = tokb + rt * 16 + quad * 4;
        *(bf16x4*)(vt + ((size_t)((b * 4 + hv) * 64 + d)) * N_ + tok) = ov;
      }
  }
}

// ---------------------------------------------------------------------------
// Output projection: A = attn output (bf16), B^T = woT bf16, C = float out.
__global__ __launch_bounds__(256) void gemm_out(const bf16* __restrict__ A,
                                                const bf16* __restrict__ Bt,
                                                float* __restrict__ C) {
  __shared__ __align__(16) bf16 As[128 * 72];
  __shared__ __align__(16) bf16 Bs[128 * 72];
  int m0 = blockIdx.x * 128, n0 = blockIdx.y * 128;
  int tid = threadIdx.x;
  int wave = tid >> 6, lane = tid & 63;
  int quad = lane >> 4, lr = lane & 15;
  int wr = (wave >> 1) * 64, wc = (wave & 1) * 64;
  int brow = tid >> 3, boff = (tid & 7) * 8;

  f32x4 acc[4][4];
  const f32x4 z = {0.f, 0.f, 0.f, 0.f};
#pragma unroll
  for (int i = 0; i < 4; ++i)
#pragma unroll
    for (int j = 0; j < 4; ++j) acc[i][j] = z;

  bf16x8 sa[4], sb[4];
#pragma unroll
  for (int i = 0; i < 4; ++i) {
    sa[i] = *(const bf16x8*)(A + (size_t)(m0 + brow + i * 32) * 1024 + boff);
    sb[i] = *(const bf16x8*)(Bt + (size_t)(n0 + brow + i * 32) * 1024 + boff);
  }
#pragma unroll
  for (int i = 0; i < 4; ++i) {
    *(bf16x8*)(As + (brow + i * 32) * 72 + boff) = sa[i];
    *(bf16x8*)(Bs + (brow + i * 32) * 72 + boff) = sb[i];
  }
  asm volatile("s_waitcnt lgkmcnt(0)" ::: "memory");
  __builtin_amdgcn_s_barrier();
  __builtin_amdgcn_sched_barrier(0);

  for (int k0 = 0; k0 < 1024; k0 += 64) {
    bool pf = (k0 + 64 < 1024);
    if (pf) {
#pragma unroll
      for (int i = 0; i < 4; ++i) {
        sa[i] = *(const bf16x8*)(A + (size_t)(m0 + brow + i * 32) * 1024 + k0 + 64 + boff);
        sb[i] = *(const bf16x8*)(Bt + (size_t)(n0 + brow + i * 32) * 1024 + k0 + 64 + boff);
      }
    }
#pragma unroll
    for (int kx = 0; kx < 2; ++kx) {
      bf16x8 af[4], bfr[4];
#pragma unroll
      for (int t = 0; t < 4; ++t) {
        af[t] = *(const bf16x8*)(As + (wr + t * 16 + lr) * 72 + kx * 32 + quad * 8);
        bfr[t] = *(const bf16x8*)(Bs + (wc + t * 16 + lr) * 72 + kx * 32 + quad * 8);
      }
      __builtin_amdgcn_s_setprio(1);
#pragma unroll
      for (int rt = 0; rt < 4; ++rt)
#pragma unroll
        for (int ct = 0; ct < 4; ++ct)
          acc[rt][ct] = __builtin_amdgcn_mfma_f32_16x16x32_bf16(af[rt], bfr[ct],
                                                                acc[rt][ct], 0, 0, 0);
      __builtin_amdgcn_s_setprio(0);
    }
    __builtin_amdgcn_s_barrier();
    __builtin_amdgcn_sched_barrier(0);
    if (pf) {
#pragma unroll
      for (int i = 0; i < 4; ++i) {
        *(bf16x8*)(As + (brow + i * 32) * 72 + boff) = sa[i];
        *(bf16x8*)(Bs + (brow + i * 32) * 72 + boff) = sb[i];
      }
      asm volatile("s_waitcnt lgkmcnt(0)" ::: "memory");
    }
    __builtin_amdgcn_s_barrier();
    __builtin_amdgcn_sched_barrier(0);
  }
#pragma unroll
  for (int rt = 0; rt < 4; ++rt)
#pragma unroll
    for (int ct = 0; ct < 4; ++ct)
#pragma unroll
      for (int r = 0; r < 4; ++r) {
        int row = m0 + wr + rt * 16 + quad * 4 + r;
        int col = n0 + wc + ct * 16 + lr;
        C[(size_t)row * 1024 + col] = acc[rt][ct][r];
      }
}

// ---------------------------------------------------------------------------
// Causal flash attention with GQA — TRANSPOSED dataflow (S^T / O^T),
// XOR-swizzled LDS, no-shift softmax, complement-pair schedule + XCD swizzle,
// double-buffered Ks/Vs (one barrier per k-tile).
// K is in a K-only buffer (stride 256); v goes straight to vt in the QKV
// epilogue, so the old kv-V half and transpose_v round-trip are gone.
__global__ __launch_bounds__(256) void attn(bf16* __restrict__ q,
                                            const bf16* __restrict__ kv,
                                            const bf16* __restrict__ vt) {
  __shared__ __align__(16) bf16 Ks[2][64 * 64];  // [buf][key][d], swizzled
  __shared__ __align__(16) bf16 Vs[2][64 * 64];  // [buf][d][key], swizzled
  __shared__ __align__(16) bf16 Ps[64 * 64];     // [q-row][key], swizzled
  int bid = blockIdx.x;
  int orig = (bid & 7) * 128 + (bid >> 3);  // bijective (1024 % 8 == 0)
  int grp = orig >> 6;                      // (b,hkv) group, 0..15
  int inner = orig & 63;
  int b = grp >> 2, hkv = grp & 3;
  int h = hkv * 4 + (inner & 3);
  int p = inner >> 2;                       // pair index, 0..15
  int tid = threadIdx.x;
  int wave = tid >> 6, lane = tid & 63;
  int quad = lane >> 4, lr = lane & 15;
  int srow = tid >> 3, soff = (tid & 7) * 8;
  int su = ((tid & 7) ^ (srow & 7)) * 8;  // swizzled LDS unit (same for srow+32)
  int e7 = lr & 7;                        // read-side row XOR key
  const f32x4 z = {0.f, 0.f, 0.f, 0.f};

#pragma unroll 1
  for (int s = 0; s < 2; ++s) {
    int j = s ? (31 - p) : p;  // q-tile index; costs sum to 33 units
    __syncthreads();           // prev sub-item's last reads done before re-stage
    int qrow0 = j * 64 + wave * 16;  // this wave's first q-row
    int nkt = j + 1;

    // Q fragments (B-operand = Q^T): lane holds Q[qrow0+lr][kx*32+quad*8..]
    bf16x8 qf[2];
#pragma unroll
    for (int kx = 0; kx < 2; ++kx)
      qf[kx] = *(const bf16x8*)(
          q + ((size_t)(b * N_ + qrow0 + lr) * H_ + h) * D_ + kx * 32 + quad * 8);

    f32x4 acc[4];  // acc[dt] = O^T tile: row d=dt*16+quad*4+r, col qrow=lr
    float l_i = 0.f;
#pragma unroll
    for (int dt = 0; dt < 4; ++dt) acc[dt] = z;

    // staging pointers (strength-reduced; advance per tile). K stride = 256.
    const bf16* kp = kv + (size_t)(b * N_ + srow) * 256 + hkv * 64 + soff;
    const bf16* vp = vt + ((size_t)(b * HKV_ + hkv) * 64 + srow) * N_ + soff;

    // ---- prologue: stage tile 0 into buf0; issue tile-1 loads
    bf16x8 sk0, sk1, sv0, sv1;
    sk0 = *(const bf16x8*)(kp);
    sk1 = *(const bf16x8*)(kp + 32 * 256);
    sv0 = *(const bf16x8*)(vp);
    sv1 = *(const bf16x8*)(vp + 32 * N_);
    *(bf16x8*)(Ks[0] + srow * 64 + su) = sk0;
    *(bf16x8*)(Ks[0] + (srow + 32) * 64 + su) = sk1;
    *(bf16x8*)(Vs[0] + srow * 64 + su) = sv0;
    *(bf16x8*)(Vs[0] + (srow + 32) * 64 + su) = sv1;
    if (nkt > 1) {
      kp += 64 * 256;
      vp += 64;
      sk0 = *(const bf16x8*)(kp);
      sk1 = *(const bf16x8*)(kp + 32 * 256);
      sv0 = *(const bf16x8*)(vp);
      sv1 = *(const bf16x8*)(vp + 32 * N_);
    }
    asm volatile("s_waitcnt lgkmcnt(0)" ::: "memory");
    __builtin_amdgcn_s_barrier();
    __builtin_amdgcn_sched_barrier(0);

    int cur = 0;
    for (int kt = 0; kt < nkt; ++kt) {
      const bf16* Kc = Ks[cur];
      const bf16* Vc = Vs[cur];
      // S^T = K·Q^T: st[ct] — key = kt*64 + ct*16 + quad*4 + r, qrow col = lr
      f32x4 st[4];
#pragma unroll
      for (int ct = 0; ct < 4; ++ct) st[ct] = z;
#pragma unroll
      for (int kx = 0; kx < 2; ++kx) {
        bf16x8 kf[4];
#pragma unroll
        for (int ct = 0; ct < 4; ++ct)
          kf[ct] = *(const bf16x8*)(Kc + (ct * 16 + lr) * 64 + (((kx * 4 + quad) ^ e7) * 8));
        __builtin_amdgcn_s_setprio(1);
#pragma unroll
        for (int ct = 0; ct < 4; ++ct)
          st[ct] = __builtin_amdgcn_mfma_f32_16x16x32_bf16(kf[ct], qf[kx], st[ct], 0, 0, 0);
        __builtin_amdgcn_s_setprio(0);
      }
      // Causal mask — only the diagonal tile kt == j crosses the diagonal
      if (kt == j) {
        int qrow = qrow0 + lr;
#pragma unroll
        for (int ct = 0; ct < 4; ++ct)
#pragma unroll
          for (int r = 0; r < 4; ++r) {
            int key = kt * 64 + ct * 16 + quad * 4 + r;
            if (key > qrow) st[ct][r] = NEGINF;
          }
      }
      // No-shift softmax: p = exp2(s) directly (|s| <= 17.32 by RMS bound);
      // masked entries exp2(-1e30) = 0. l accumulates unnormalized.
      float rs = 0.f;
#pragma unroll
      for (int ct = 0; ct < 4; ++ct)
#pragma unroll
        for (int r = 0; r < 4; ++r) {
          float pv = exp2f(st[ct][r]);
          st[ct][r] = pv;
          rs += pv;
        }
      rs += __shfl_xor(rs, 16);
      rs += __shfl_xor(rs, 32);
      l_i += rs;
      // P^T -> Ps[qrow][key] (swizzled): b64 writes, keys quad*4+r contiguous
#pragma unroll
      for (int ct = 0; ct < 4; ++ct) {
        bf16x4 pk;
#pragma unroll
        for (int r = 0; r < 4; ++r) pk[r] = (bf16)st[ct][r];
        int pu = (((ct * 2) + (quad >> 1)) ^ e7) * 8 + (quad & 1) * 4;
        *(bf16x4*)(Ps + (wave * 16 + lr) * 64 + pu) = pk;
      }
      // Wave-local LDS ordering (rows wave-private, guard wave-uniform)
      asm volatile("s_waitcnt lgkmcnt(0)" ::: "memory");
      // O^T += V^T·P^T
#pragma unroll
      for (int kx = 0; kx < 2; ++kx) {
        bf16x8 vf[4], pfr;
#pragma unroll
        for (int dt = 0; dt < 4; ++dt)
          vf[dt] = *(const bf16x8*)(Vc + (dt * 16 + lr) * 64 + (((kx * 4 + quad) ^ e7) * 8));
        pfr = *(const bf16x8*)(Ps + (wave * 16 + lr) * 64 + (((kx * 4 + quad) ^ e7) * 8));
        __builtin_amdgcn_s_setprio(1);
#pragma unroll
        for (int dt = 0; dt < 4; ++dt)
          acc[dt] = __builtin_amdgcn_mfma_f32_16x16x32_bf16(vf[dt], pfr, acc[dt], 0, 0, 0);
        __builtin_amdgcn_s_setprio(0);
      }

      // ---- stage tile kt+1 into the OTHER buffer (no WAR: readers use cur).
      bool pf = (kt + 1 < nkt);
      if (pf) {
        bf16* Kn = Ks[cur ^ 1];
        bf16* Vn = Vs[cur ^ 1];
        *(bf16x8*)(Kn + srow * 64 + su) = sk0;
        *(bf16x8*)(Kn + (srow + 32) * 64 + su) = sk1;
        *(bf16x8*)(Vn + srow * 64 + su) = sv0;
        *(bf16x8*)(Vn + (srow + 32) * 64 + su) = sv1;
        if (kt + 2 < nkt) {
          kp += 64 * 256;
          vp += 64;
          sk0 = *(const bf16x8*)(kp);
          sk1 = *(const bf16x8*)(kp + 32 * 256);
          sv0 = *(const bf16x8*)(vp);
          sv1 = *(const bf16x8*)(vp + 32 * N_);
        }
        asm volatile("s_waitcnt lgkmcnt(0)" ::: "memory");
      }
      // ONE barrier per tile: all waves wrote buf^1 and finished reading cur.
      __builtin_amdgcn_s_barrier();
      __builtin_amdgcn_sched_barrier(0);
      cur ^= 1;
    }

    // Epilogue: y = O / l — lane owns q-row lr, d = dt*16+quad*4+r
    float inv = 1.0f / l_i;
    int qrow = qrow0 + lr;
#pragma unroll
    for (int dt = 0; dt < 4; ++dt) {
      bf16x4 ov;
#pragma unroll
      for (int r = 0; r < 4; ++r) ov[r] = (bf16)(acc[dt][r] * inv);
      *(bf16x4*)(q + ((size_t)(b * N_ + qrow) * H_ + h) * D_ + dt * 16 + quad * 4) = ov;
    }
  }
}

// ---------------------------------------------------------------------------
extern "C" void kernel_launch(void* const* d_in, const int* in_sizes, int n_in,
                              void* d_out, int out_size, void* d_ws, size_t ws_size,
                              hipStream_t stream) {
  // Inputs FP32; output FP32. Intermediates bf16.
  const float* x = (const float*)d_in[0];
  const float* wq = (const float*)d_in[1];
  const float* wk = (const float*)d_in[2];
  const float* wv = (const float*)d_in[3];
  const float* wo = (const float*)d_in[4];
  float* out = (float*)d_out;
  char* ws = (char*)d_ws;
  // ws (28 MB): q/y 16 MB [0,16M) | kvK 4 MB [16M,20M) | vt 4 MB [20M,24M)
  //           | [24M,27M): wqkvT (3 MB, dead after gemm_qkv) -> woT (2 MB).
  bf16* q = (bf16*)(ws);
  bf16* kvK = (bf16*)(ws + 16777216);
  bf16* vt = (bf16*)(ws + 20971520);
  bf16* wqkvT = (bf16*)(ws + 25165824);
  bf16* woT = (bf16*)(ws + 25165824);

  prep_qkv<<<dim3(384), 256, 0, stream>>>(wq, wk, wv, wqkvT);
  gemm_qkv<<<dim3(64, 12), 256, 0, stream>>>(x, wqkvT, q, kvK, vt);
  attn<<<dim3(1024), 256, 0, stream>>>(q, kvK, vt);
  prep_wo<<<dim3(256), 256, 0, stream>>>(wo, woT);
  gemm_out<<<dim3(64, 8), 256, 0, stream>>>(q, woT, out);
}